// Round 1
// 503.300 us; speedup vs baseline: 1.0305x; 1.0305x over previous
//
#include <hip/hip_runtime.h>

// PosEncoding: out[n][d] = (d even ? sin : cos)(positions[n] * w_k[d]),
// zeroed where positions[n] == 0.  N = 1e6, D = 128.
//
// Memory-bound: 512 MB write-only output. Layout: 32 lanes per row, each
// lane owns one float4 column slice (16 B), and each lane-group of 32
// threads now processes ROWS=8 consecutive rows. This cuts wave count 8x
// (500K -> 62.5K) to amortize per-wave setup (kernarg loads, address calc,
// preamble waits) that dominated when each wave wrote only 1 KiB.
//
// Per-element math is bit-identical to the previous version (same multiply
// order, same builtins) to keep absmax at 0.00390625.

#define D_WORD 128
#define ROWS 8

// clang native vector type (HIP's float4 is a struct; the nontemporal
// builtin only takes scalar/native-vector pointers)
typedef float f32x4 __attribute__((ext_vector_type(4)));

__global__ __launch_bounds__(256) void posenc_kernel(
    const float* __restrict__ positions,
    const float* __restrict__ w_k,
    float* __restrict__ out,
    int n_pos) {
    int tid  = blockIdx.x * blockDim.x + threadIdx.x;
    int grp  = tid >> 5;          // lane-group: 32 lanes handle ROWS rows
    int lane = tid & 31;
    long long rowbase = (long long)grp * ROWS;
    if (rowbase >= n_pos) return;

    int d4 = lane << 2;           // 0,4,...,124 — 16B aligned into w_k and out row
    f32x4 w = *(const f32x4*)(w_k + d4);   // w.x==w.y (freq 2k), w.z==w.w (freq 2k+1)

    // hardware v_sin/v_cos take REVOLUTIONS; reduce manually (angle up to 8192 rad)
    const float inv2pi = 0.15915494309189535f;

    float* orow = out + (size_t)rowbase * D_WORD + d4;

    if (rowbase + ROWS <= n_pos) {
        // fast path: 8 positions via two broadcast 16B loads (rowbase % 8 == 0)
        f32x4 p0 = *(const f32x4*)(positions + rowbase);
        f32x4 p1 = *(const f32x4*)(positions + rowbase + 4);

        #pragma unroll
        for (int r = 0; r < ROWS; ++r) {
            float p = (r < 4) ? p0[r] : p1[r - 4];  // constant idx after unroll
            float r0 = p * w.x * inv2pi;
            float r1 = p * w.z * inv2pi;
            r0 = r0 - floorf(r0);
            r1 = r1 - floorf(r1);
            f32x4 o;
            o.x = __builtin_amdgcn_sinf(r0);   // d4+0 even -> sin
            o.y = __builtin_amdgcn_cosf(r0);   // d4+1 odd  -> cos
            o.z = __builtin_amdgcn_sinf(r1);   // d4+2 even -> sin
            o.w = __builtin_amdgcn_cosf(r1);   // d4+3 odd  -> cos
            if (p == 0.0f) { o = (f32x4){0.f, 0.f, 0.f, 0.f}; }
            // stores share one 64-bit base; r*512B folds into offset imm
            __builtin_nontemporal_store(o, (f32x4*)(orow + (size_t)r * D_WORD));
        }
    } else {
        // tail (unused for N=1e6, kept for generality)
        for (int r = 0; r < ROWS; ++r) {
            if (rowbase + r >= n_pos) break;
            float p = positions[rowbase + r];
            float r0 = p * w.x * inv2pi;
            float r1 = p * w.z * inv2pi;
            r0 = r0 - floorf(r0);
            r1 = r1 - floorf(r1);
            f32x4 o;
            o.x = __builtin_amdgcn_sinf(r0);
            o.y = __builtin_amdgcn_cosf(r0);
            o.z = __builtin_amdgcn_sinf(r1);
            o.w = __builtin_amdgcn_cosf(r1);
            if (p == 0.0f) { o = (f32x4){0.f, 0.f, 0.f, 0.f}; }
            __builtin_nontemporal_store(o, (f32x4*)(orow + (size_t)r * D_WORD));
        }
    }
}

extern "C" void kernel_launch(void* const* d_in, const int* in_sizes, int n_in,
                              void* d_out, int out_size, void* d_ws, size_t ws_size,
                              hipStream_t stream) {
    const float* positions = (const float*)d_in[0];
    const float* w_k       = (const float*)d_in[1];
    float* out             = (float*)d_out;
    int n_pos = in_sizes[0];               // 1,000,000

    // one lane-group (32 threads) per 8 rows; 256 threads/block => 64 rows/block
    long long groups        = ((long long)n_pos + ROWS - 1) / ROWS;
    long long total_threads = groups * 32;
    int block = 256;
    int grid  = (int)((total_threads + block - 1) / block);

    posenc_kernel<<<grid, block, 0, stream>>>(positions, w_k, out, n_pos);
}

// Round 2
// 502.506 us; speedup vs baseline: 1.0322x; 1.0016x over previous
//
#include <hip/hip_runtime.h>

// PosEncoding: out[n][d] = (d even ? sin : cos)(positions[n] * w_k[d]),
// zeroed where positions[n] == 0.  N = 1e6, D = 128.
//
// Memory-bound: 512 MB write-only output.
//
// Layout v3: each WAVE (64 lanes) handles RPW=16 consecutive rows.
//   lane = 64-lane index; hi = lane>>5 picks row-within-pair; l32 = lane&31
//   picks the float4 column slice. Store instruction r writes rows
//   (rowbase + 2r + hi) -> one fully CONTIGUOUS 1 KiB segment per wave
//   store (round 1's lane-group layout split every store into two 512 B
//   segments 4 KiB apart; round 0 was contiguous but 2 rows/wave).
//   16 rows/wave keeps wave count at 62.5K for setup amortization.
//
// Per-element math is op-for-op identical to previous versions (same
// multiply order, same builtins) to keep absmax at 0.00390625.

#define D_WORD 128
#define RPW 16   // rows per wave

typedef float f32x4 __attribute__((ext_vector_type(4)));

__global__ __launch_bounds__(256) void posenc_kernel(
    const float* __restrict__ positions,
    const float* __restrict__ w_k,
    float* __restrict__ out,
    int n_pos) {
    int tid  = blockIdx.x * blockDim.x + threadIdx.x;
    int wid  = tid >> 6;           // wave index: 16 rows per wave
    int lane = tid & 63;
    int hi   = lane >> 5;          // row-within-pair
    int l32  = lane & 31;          // column slice
    long long rowbase = (long long)wid * RPW;
    if (rowbase >= n_pos) return;

    int d4 = l32 << 2;             // 0,4,...,124 — 16B aligned into w_k and out row
    f32x4 w = *(const f32x4*)(w_k + d4);  // w.x==w.y (freq 2k), w.z==w.w (freq 2k+1)

    // hardware v_sin/v_cos take REVOLUTIONS; reduce manually (angle up to 8192 rad)
    const float inv2pi = 0.15915494309189535f;

    // store r writes row rowbase + 2r + hi at column d4
    float* obase = out + ((size_t)rowbase + hi) * D_WORD + d4;

    if (rowbase + RPW <= n_pos) {
        // 16 positions via four broadcast 16B loads (rowbase % 16 == 0)
        float pv[RPW];
        *(f32x4*)(pv +  0) = *(const f32x4*)(positions + rowbase);
        *(f32x4*)(pv +  4) = *(const f32x4*)(positions + rowbase + 4);
        *(f32x4*)(pv +  8) = *(const f32x4*)(positions + rowbase + 8);
        *(f32x4*)(pv + 12) = *(const f32x4*)(positions + rowbase + 12);

        #pragma unroll
        for (int r = 0; r < RPW / 2; ++r) {
            // constant indices after unroll -> stays in registers
            float pe = pv[2 * r];
            float po = pv[2 * r + 1];
            float p  = hi ? po : pe;            // one v_cndmask

            float r0 = p * w.x * inv2pi;
            float r1 = p * w.z * inv2pi;
            r0 = r0 - floorf(r0);
            r1 = r1 - floorf(r1);
            f32x4 o;
            o.x = __builtin_amdgcn_sinf(r0);    // d4+0 even -> sin
            o.y = __builtin_amdgcn_cosf(r0);    // d4+1 odd  -> cos
            o.z = __builtin_amdgcn_sinf(r1);    // d4+2 even -> sin
            o.w = __builtin_amdgcn_cosf(r1);    // d4+3 odd  -> cos
            if (p == 0.0f) { o = (f32x4){0.f, 0.f, 0.f, 0.f}; }

            // wave-contiguous 1 KiB store; r*1024B folds into offset imm
            __builtin_nontemporal_store(o, (f32x4*)(obase + (size_t)r * (2 * D_WORD)));
        }
    } else {
        // tail (unused for N=1e6, kept for generality)
        for (int r = 0; r < RPW / 2; ++r) {
            long long row = rowbase + 2 * r + hi;
            if (row >= n_pos) continue;
            float p = positions[row];
            float r0 = p * w.x * inv2pi;
            float r1 = p * w.z * inv2pi;
            r0 = r0 - floorf(r0);
            r1 = r1 - floorf(r1);
            f32x4 o;
            o.x = __builtin_amdgcn_sinf(r0);
            o.y = __builtin_amdgcn_cosf(r0);
            o.z = __builtin_amdgcn_sinf(r1);
            o.w = __builtin_amdgcn_cosf(r1);
            if (p == 0.0f) { o = (f32x4){0.f, 0.f, 0.f, 0.f}; }
            __builtin_nontemporal_store(o, (f32x4*)(obase + (size_t)r * (2 * D_WORD)));
        }
    }
}

extern "C" void kernel_launch(void* const* d_in, const int* in_sizes, int n_in,
                              void* d_out, int out_size, void* d_ws, size_t ws_size,
                              hipStream_t stream) {
    const float* positions = (const float*)d_in[0];
    const float* w_k       = (const float*)d_in[1];
    float* out             = (float*)d_out;
    int n_pos = in_sizes[0];               // 1,000,000

    // one wave (64 threads) per 16 rows; 256 threads/block => 64 rows/block
    long long waves         = ((long long)n_pos + RPW - 1) / RPW;
    long long total_threads = waves * 64;
    int block = 256;
    int grid  = (int)((total_threads + block - 1) / block);

    posenc_kernel<<<grid, block, 0, stream>>>(positions, w_k, out, n_pos);
}